// Round 14
// baseline (955.982 us; speedup 1.0000x reference)
//
#include <hip/hip_runtime.h>
#include <hip/hip_bf16.h>
#include <stdint.h>

typedef __bf16 bf;
typedef __bf16 bfv8 __attribute__((ext_vector_type(8)));
typedef __bf16 bfv4 __attribute__((ext_vector_type(4)));
typedef float  f32x4 __attribute__((ext_vector_type(4)));

#define MFMA16(a,b,c) __builtin_amdgcn_mfma_f32_16x16x32_bf16((a),(b),(c),0,0,0)

#define CH  96
#define WID 256
#define HGT 256
#define NB  8
#define SCALE 0.1020620726159658f   // 96^-0.5

__device__ __forceinline__ float b2f(bf x){ return (float)x; }
__device__ __forceinline__ bf   f2b(float x){ return (bf)x; }

__device__ __forceinline__ bfv8 ld_cvt8(const float* __restrict__ p){
  f32x4 a = *(const f32x4*)p;
  f32x4 b = *(const f32x4*)(p + 4);
  bfv8 r;
  r[0]=f2b(a[0]); r[1]=f2b(a[1]); r[2]=f2b(a[2]); r[3]=f2b(a[3]);
  r[4]=f2b(b[0]); r[5]=f2b(b[1]); r[6]=f2b(b[2]); r[7]=f2b(b[3]);
  return r;
}
__device__ __forceinline__ bfv4 pack4(float a,float b,float c,float d){
  bfv4 r; r[0]=f2b(a); r[1]=f2b(b); r[2]=f2b(c); r[3]=f2b(d); return r;
}
__device__ __forceinline__ uint32_t pk2(float a, float b){
  union { bf h[2]; uint32_t u; } c;
  c.h[0] = f2b(a); c.h[1] = f2b(b);
  return c.u;
}

// ---------------- K_c1x1: conv1x1 GEMM, LDS-resident weights (low VGPR), prefetch ----------------
__global__ __launch_bounds__(256) void k_c1x1(
    const float* __restrict__ X,
    const float* __restrict__ Wa, const float* __restrict__ Ba,
    const float* __restrict__ Wb, const float* __restrict__ Bb,
    bf* __restrict__ Ca, bf* __restrict__ Cb)
{
  __shared__ bf wlds0[96*96];
  __shared__ bf wlds1[96*96];
  __shared__ float blds[2][96];
  const int tid=threadIdx.x, lane=tid&63, wv=tid>>6;
  const int l15=lane&15, lg=lane>>4;

  for (int k = tid; k < (96*96)/8; k += 256){
    ((bfv8*)wlds0)[k] = ld_cvt8(Wa + k*8);
    ((bfv8*)wlds1)[k] = ld_cvt8(Wb + k*8);
  }
  if (tid < 96){ blds[0][tid] = Ba[tid]; blds[1][tid] = Bb[tid]; }
  __syncthreads();

  const int set = wv&1, th = wv>>1;
  const bf* W1 = set ? wlds1 : wlds0;
  const float* B1 = blds[set];
  bf* C = set ? Cb : Ca;
  const size_t p0 = (size_t)blockIdx.x * 256;
  const int t0 = th*8;

  f32x4 bias4[6];
#pragma unroll
  for (int nt=0;nt<6;++nt)
    bias4[nt] = *(const f32x4*)(B1 + nt*16 + lg*4);

  bfv8 af[3], afn[3];
#pragma unroll
  for (int ks=0;ks<3;++ks)
    af[ks] = ld_cvt8(X + (p0 + t0*16 + l15)*CH + ks*32 + lg*8);

#pragma unroll 1
  for (int i=0;i<8;++i){
    const int m0 = (t0+i)*16;
    if (i<7){
#pragma unroll
      for (int ks=0;ks<3;++ks)
        afn[ks] = ld_cvt8(X + (p0+m0+16+l15)*CH + ks*32 + lg*8);
    }
    f32x4 acc[6];
#pragma unroll
    for (int nt=0;nt<6;++nt) acc[nt]=bias4[nt];
#pragma unroll
    for (int ks=0;ks<3;++ks)
#pragma unroll
      for (int nt=0;nt<6;++nt)
        acc[nt] = MFMA16(*(const bfv8*)(W1 + (nt*16+l15)*CH + ks*32 + lg*8),
                         af[ks], acc[nt]);   // A=W (LDS), B=X
#pragma unroll
    for (int nt=0;nt<6;++nt)
      *(bfv4*)(C + (p0+m0+l15)*CH + nt*16 + lg*4)
        = pack4(acc[nt][0],acc[nt][1],acc[nt][2],acc[nt][3]);
#pragma unroll
    for (int ks=0;ks<3;++ks) af[ks]=afn[ks];
  }
}

// ---------------- K_dw: depthwise 3x3, 2-column-deep software pipeline ----------------
__global__ __launch_bounds__(256) void k_dw(
    const bf* __restrict__ C0, const bf* __restrict__ C1,
    const float* __restrict__ WD0, const float* __restrict__ BD0,
    const float* __restrict__ WD1, const float* __restrict__ BD1,
    bf* __restrict__ O0, bf* __restrict__ O1)
{
  const int tid = threadIdx.x;
  if (tid >= 240) return;
  const int g = tid % 12, slot = tid / 12;
  const int yrow = slot >> 2, xrun = slot & 3;
  const int b = blockIdx.z >> 1, s = blockIdx.z & 1;
  const bf* C = s ? C1 : C0;
  const float* WD = s ? WD1 : WD0;
  const float* BD = s ? BD1 : BD0;
  bf* O = s ? O1 : O0;
  const int x0 = blockIdx.x*64 + xrun*16;
  const int y  = blockIdx.y*5 + yrow;
  if (y >= HGT) return;
  const size_t ib = (size_t)b * (HGT*WID) * CH;

  float wv[9][8], bb[8];
#pragma unroll
  for (int j=0;j<8;++j){
    bb[j] = BD[g*8+j];
#pragma unroll
    for (int t=0;t<9;++t) wv[t][j] = WD[(g*8+j)*9 + t];
  }

  const bf* r0 = C + ib + ((size_t)(y-1)*WID)*CH + g*8;
  const bf* r1 = C + ib + ((size_t)(y  )*WID)*CH + g*8;
  const bf* r2 = C + ib + ((size_t)(y+1)*WID)*CH + g*8;
  const bool v0 = (y > 0), v2 = (y+1 < HGT);
  const bfv8 Z = {0,0,0,0,0,0,0,0};

  bfv8 w00,w01,w02, w10,w11,w12, w20,w21,w22;
  bfv8 na0,na1,na2, nb0,nb1,nb2;
  {
    bool vx = (x0 > 0);
    size_t o = (size_t)(x0-1)*CH;
    w00 = (v0&&vx) ? *(const bfv8*)(r0+o) : Z;
    w10 = vx       ? *(const bfv8*)(r1+o) : Z;
    w20 = (v2&&vx) ? *(const bfv8*)(r2+o) : Z;
  }
  {
    size_t o = (size_t)x0*CH;
    w01 = v0 ? *(const bfv8*)(r0+o) : Z;
    w11 =      *(const bfv8*)(r1+o);
    w21 = v2 ? *(const bfv8*)(r2+o) : Z;
  }
  {
    int xn = x0+1; bool vx = (xn < WID);
    size_t o = (size_t)xn*CH;
    na0 = (v0&&vx) ? *(const bfv8*)(r0+o) : Z;
    na1 = vx       ? *(const bfv8*)(r1+o) : Z;
    na2 = (v2&&vx) ? *(const bfv8*)(r2+o) : Z;
  }
  {
    int xn = x0+2; bool vx = (xn < WID);
    size_t o = (size_t)xn*CH;
    nb0 = (v0&&vx) ? *(const bfv8*)(r0+o) : Z;
    nb1 = vx       ? *(const bfv8*)(r1+o) : Z;
    nb2 = (v2&&vx) ? *(const bfv8*)(r2+o) : Z;
  }
#pragma unroll
  for (int xi=0; xi<16; ++xi){
    w02 = na0; w12 = na1; w22 = na2;
    na0 = nb0; na1 = nb1; na2 = nb2;
    {
      int xn = x0 + xi + 3;
      bool vx = (xn < WID) && (xi < 14);
      size_t o = (size_t)xn*CH;
      nb0 = (v0&&vx) ? *(const bfv8*)(r0+o) : Z;
      nb1 = vx       ? *(const bfv8*)(r1+o) : Z;
      nb2 = (v2&&vx) ? *(const bfv8*)(r2+o) : Z;
    }
    float acc[8];
#pragma unroll
    for (int j=0;j<8;++j) acc[j] = bb[j];
#pragma unroll
    for (int j=0;j<8;++j){
      acc[j] += wv[0][j]*b2f(w00[j]);
      acc[j] += wv[1][j]*b2f(w01[j]);
      acc[j] += wv[2][j]*b2f(w02[j]);
      acc[j] += wv[3][j]*b2f(w10[j]);
      acc[j] += wv[4][j]*b2f(w11[j]);
      acc[j] += wv[5][j]*b2f(w12[j]);
      acc[j] += wv[6][j]*b2f(w20[j]);
      acc[j] += wv[7][j]*b2f(w21[j]);
      acc[j] += wv[8][j]*b2f(w22[j]);
    }
    bfv8 st;
#pragma unroll
    for (int j=0;j<8;++j) st[j] = f2b(acc[j]);
    *(bfv8*)(O + ib + ((size_t)y*WID + x0 + xi)*CH + g*8) = st;
    w00=w01; w01=w02;
    w10=w11; w11=w12;
    w20=w21; w21=w22;
  }
}

// ---------------- K_attn v7: aq eliminated via in-register shfl P-exchange ----------------
// LDS = vt[96][264] + rs[256] = 51,712 B -> 3 blocks/CU (was 2).
// P layout after swapped scores: lane(l15,lg) holds P[m=l15][v=nt*16+lg*4+r].
// PV needs lane(l15,lg) to hold P[m=l15][v=ks*32+lg*8+j]. Quad algebra:
//   srcA = l15 + ((lg&1)<<5), srcB = srcA+16, nt_s = 2ks+(lg>>1) (select by lg&2 at dest).
// F stored directly as packed bfv4 (rows fully covered -> L2 merges, no write amp).
__global__ __launch_bounds__(256) void k_attn(
    const bf* __restrict__ Ql, const bf* __restrict__ Qr,
    bf* Vl, bf* Vr)
{
  extern __shared__ char sm[];
  bf* vt = (bf*)sm;                          // [96][264] = 50,688 B
  float* rs = (float*)(sm + 96*264*2);       // [256] = 1,024 B
  const int tid=threadIdx.x, lane=tid&63, wid=tid>>6;
  const int l15=lane&15, lg=lane>>4;
  const int bh = blockIdx.x;
  const size_t qoff = (size_t)bh * (WID*CH);
  const int srcA = l15 + ((lg&1)<<5);
  const int srcB = srcA + 16;
  const bool h2 = (lg&2)!=0;

#pragma unroll 1
  for (int phase=0; phase<2; ++phase) {
    const bf* msrc = phase ? Qr+qoff : Ql+qoff;
    const bf* nsrc = phase ? Ql+qoff : Qr+qoff;
    bf* Vp = (phase ? Vl : Vr) + qoff;       // staged then overwritten with F
    if (phase) {
      __syncthreads();               // phase-0 vt reads + rs writes done
      rs[tid] = SCALE / rs[tid];     // rs -> fw table
    }
    { // stage V^T
      const bfv8* src = (const bfv8*)(Vp + (size_t)tid*CH);
#pragma unroll
      for (int i=0;i<12;++i){
        bfv8 v8 = src[i];
#pragma unroll
        for (int j=0;j<8;++j) vt[(i*8+j)*264 + tid] = v8[j];
      }
    }
    __syncthreads();                 // vt ready (+ fw published); Vp rows now dead

#pragma unroll 1
    for (int qp=0; qp<2; ++qp){
      bfv8 af2[2][3];
#pragma unroll
      for (int q01=0;q01<2;++q01){
        const int m0 = (qp*2+q01)*64 + wid*16;
#pragma unroll
        for (int ks=0;ks<3;++ks)
          af2[q01][ks] = *(const bfv8*)(msrc + (size_t)(m0+l15)*CH + ks*32 + lg*8);
      }
      f32x4 o[2][6];
#pragma unroll
      for (int q01=0;q01<2;++q01)
#pragma unroll
        for (int nt=0;nt<6;++nt) o[q01][nt]=(f32x4){0.f,0.f,0.f,0.f};
      float rsum2[2]={0.f,0.f};

#pragma unroll 1
      for (int c4=0;c4<4;++c4){
        bfv8 nb[4][3];
#pragma unroll
        for (int nt=0;nt<4;++nt)
#pragma unroll
          for (int ks=0;ks<3;++ks)
            nb[nt][ks] = *(const bfv8*)(nsrc + (size_t)(c4*64+nt*16+l15)*CH + ks*32+lg*8);
        f32x4 fwv4[4];
        if (phase){
#pragma unroll
          for (int nt=0;nt<4;++nt)
            fwv4[nt] = *(const f32x4*)(rs + c4*64 + nt*16 + lg*4);
        }
#pragma unroll
        for (int q01=0;q01<2;++q01){
          f32x4 acc[4];
#pragma unroll
          for (int nt=0;nt<4;++nt) acc[nt]=(f32x4){0.f,0.f,0.f,0.f};
#pragma unroll
          for (int ks=0;ks<3;++ks)
#pragma unroll
            for (int nt=0;nt<4;++nt)
              acc[nt]=MFMA16(nb[nt][ks], af2[q01][ks], acc[nt]);
          // ---- exp -> packed bf16 dwords (dlo=r0,r1; dhi=r2,r3) ----
          uint32_t dlo[4], dhi[4];
          if (phase==0){
#pragma unroll
            for (int nt=0;nt<4;++nt){
              float e0=__expf(acc[nt][0]), e1=__expf(acc[nt][1]);
              float e2=__expf(acc[nt][2]), e3=__expf(acc[nt][3]);
              rsum2[q01] += (e0+e1)+(e2+e3);
              dlo[nt]=pk2(e0,e1); dhi[nt]=pk2(e2,e3);
            }
          } else {
#pragma unroll
            for (int nt=0;nt<4;++nt){
              float e0=__expf(acc[nt][0])*fwv4[nt][0];
              float e1=__expf(acc[nt][1])*fwv4[nt][1];
              float e2=__expf(acc[nt][2])*fwv4[nt][2];
              float e3=__expf(acc[nt][3])*fwv4[nt][3];
              dlo[nt]=pk2(e0,e1); dhi[nt]=pk2(e2,e3);
            }
          }
          // ---- shfl exchange -> PV A-row fragments, then PV MFMAs ----
#pragma unroll
          for (int ks=0;ks<2;++ks){
            int A0=__shfl((int)dlo[2*ks],  srcA,64), A1=__shfl((int)dhi[2*ks],  srcA,64);
            int B0=__shfl((int)dlo[2*ks+1],srcA,64), B1=__shfl((int)dhi[2*ks+1],srcA,64);
            int C0=__shfl((int)dlo[2*ks],  srcB,64), C1=__shfl((int)dhi[2*ks],  srcB,64);
            int D0=__shfl((int)dlo[2*ks+1],srcB,64), D1=__shfl((int)dhi[2*ks+1],srcB,64);
            union { uint32_t d[4]; bfv8 v; } U;
            U.d[0] = h2?(uint32_t)B0:(uint32_t)A0;
            U.d[1] = h2?(uint32_t)B1:(uint32_t)A1;
            U.d[2] = h2?(uint32_t)D0:(uint32_t)C0;
            U.d[3] = h2?(uint32_t)D1:(uint32_t)C1;
            bfv8 aa = U.v;
#pragma unroll
            for (int nt=0;nt<6;++nt)
              o[q01][nt]=MFMA16(
                *(const bfv8*)(vt + (nt*16+l15)*264 + c4*64 + ks*32 + lg*8),
                aa, o[q01][nt]);
          }
        }
      }
      // ---- finalize: deferred scale + direct packed bfv4 F stores ----
#pragma unroll
      for (int q01=0;q01<2;++q01){
        const int m0 = (qp*2+q01)*64 + wid*16;
        float sc;
        if (phase==0){
          float rsv = rsum2[q01];
          rsv += __shfl_xor(rsv, 16, 64);
          rsv += __shfl_xor(rsv, 32, 64);
          if (lane < 16) rs[m0 + l15] = rsv;
          sc = SCALE / rsv;
        } else sc = 1.f;
#pragma unroll
        for (int nt=0;nt<6;++nt)
          *(bfv4*)(Vp + (size_t)(m0+l15)*CH + nt*16 + lg*4)
            = pack4(o[q01][nt][0]*sc, o[q01][nt][1]*sc,
                    o[q01][nt][2]*sc, o[q01][nt][3]*sc);
      }
    }
  }
}

// ---------------- K_wprep ----------------
__global__ __launch_bounds__(256) void k_wprep(
    const float* __restrict__ L, const float* __restrict__ lb,
    const float* __restrict__ R, const float* __restrict__ rb,
    const float* __restrict__ D, const float* __restrict__ db,
    const float* __restrict__ beta, const float* __restrict__ gamma,
    bf* __restrict__ Wcat, float* __restrict__ bv)
{
  const int o = blockIdx.x;
  const int tid = threadIdx.x;
  for (int k = tid; k < 384; k += 256){
    float v;
    if (k < 192) v = D[o*192 + k];
    else if (k < 288){
      int c = k - 192; float s = 0.f;
      for (int m=0;m<96;++m) s += D[o*192+m]*beta[m]*L[m*96+c];
      v = s;
    } else {
      int c = k - 288; float s = 0.f;
      for (int m=0;m<96;++m) s += D[o*192+96+m]*gamma[m]*R[m*96+c];
      v = s;
    }
    Wcat[o*384+k] = f2b(v);
  }
  if (tid == 0){
    float s = db[o];
    for (int m=0;m<96;++m) s += D[o*192+m]*beta[m]*lb[m] + D[o*192+96+m]*gamma[m]*rb[m];
    bv[o] = s;
  }
}

// ---------------- K_fuse v4: LDS-free + next-tile prefetch ----------------
__global__ __launch_bounds__(256) void k_fuse(
    const float* __restrict__ I1, const float* __restrict__ I2,
    const bf* __restrict__ F1, const bf* __restrict__ F2,
    const bf* __restrict__ Wcat, const float* __restrict__ bv,
    float* __restrict__ OUT)
{
  const int tid=threadIdx.x, lane=tid&63, wv=tid>>6;
  const int l15=lane&15, lg=lane>>4;
  const int half = wv&1, pair = wv>>1;
  const size_t p0 = (size_t)blockIdx.x * 128;

  bfv8 wf[12][3];
  f32x4 bias4[3];
#pragma unroll
  for (int j=0;j<3;++j){
    int c = (half*3+j)*16;
    bias4[j] = *(const f32x4*)(bv + c + lg*4);
#pragma unroll
    for (int kb=0;kb<12;++kb)
      wf[kb][j] = *(const bfv8*)(Wcat + (size_t)(c+l15)*384 + kb*32 + lg*8);
  }

  bfv8 a[12], an[12];
  {
    const size_t m0 = p0 + pair*4*16;
    const float* x1 = I1 + (m0+l15)*CH + lg*8;
    const float* x2 = I2 + (m0+l15)*CH + lg*8;
    const bf* f1 = F1 + (m0+l15)*CH + lg*8;
    const bf* f2 = F2 + (m0+l15)*CH + lg*8;
#pragma unroll
    for (int ks=0;ks<3;++ks){
      a[ks]   = ld_cvt8(x1 + ks*32);
      a[3+ks] = ld_cvt8(x2 + ks*32);
      a[6+ks] = *(const bfv8*)(f1 + ks*32);
      a[9+ks] = *(const bfv8*)(f2 + ks*32);
    }
  }
#pragma unroll 1
  for (int i=0;i<4;++i){
    const size_t m0 = p0 + (pair*4+i)*16;
    if (i<3){
      const size_t mn = m0 + 16;
      const float* x1 = I1 + (mn+l15)*CH + lg*8;
      const float* x2 = I2 + (mn+l15)*CH + lg*8;
      const bf* f1 = F1 + (mn+l15)*CH + lg*8;
      const bf* f2 = F2 + (mn+l15)*CH + lg*8;
#pragma unroll
      for (int ks=0;ks<3;++ks){
        an[ks]   = ld_cvt8(x1 + ks*32);
        an[3+ks] = ld_cvt8(x2 + ks*32);
        an[6+ks] = *(const bfv8*)(f1 + ks*32);
        an[9+ks] = *(const bfv8*)(f2 + ks*32);
      }
    }
    f32x4 acc[3];
#pragma unroll
    for (int j=0;j<3;++j) acc[j]=bias4[j];
#pragma unroll
    for (int kb=0;kb<12;++kb)
#pragma unroll
      for (int j=0;j<3;++j)
        acc[j] = MFMA16(wf[kb][j], a[kb], acc[j]);   // A=W, B=[x|F]
#pragma unroll
    for (int j=0;j<3;++j)
      *(f32x4*)(OUT + (m0+l15)*CH + (half*3+j)*16 + lg*4) = acc[j];
#pragma unroll
    for (int kb=0;kb<12;++kb) a[kb]=an[kb];
  }
}

extern "C" void kernel_launch(void* const* d_in, const int* in_sizes, int n_in,
                              void* d_out, int out_size, void* d_ws, size_t ws_size,
                              hipStream_t stream)
{
  (void)in_sizes; (void)n_in; (void)out_size; (void)ws_size;
  const float* I1 = (const float*)d_in[0];
  const float* I2 = (const float*)d_in[1];
  const float* se1_w = (const float*)d_in[4];
  const float* se1_b = (const float*)d_in[5];
  const float* se1_dw= (const float*)d_in[6];
  const float* se1_db= (const float*)d_in[7];
  const float* se2_w = (const float*)d_in[8];
  const float* se2_b = (const float*)d_in[9];
  const float* se2_dw= (const float*)d_in[10];
  const float* se2_db= (const float*)d_in[11];
  const float* lp1_w = (const float*)d_in[12];
  const float* lp1_b = (const float*)d_in[13];
  const float* lp1_dw= (const float*)d_in[14];
  const float* lp1_db= (const float*)d_in[15];
  const float* rp1_w = (const float*)d_in[16];
  const float* rp1_b = (const float*)d_in[17];
  const float* rp1_dw= (const float*)d_in[18];
  const float* rp1_db= (const float*)d_in[19];
  const float* lp2_w = (const float*)d_in[20];
  const float* lp2_b = (const float*)d_in[21];
  const float* rp2_w = (const float*)d_in[22];
  const float* rp2_b = (const float*)d_in[23];
  const float* down_w= (const float*)d_in[24];
  const float* down_b= (const float*)d_in[25];
  const float* beta  = (const float*)d_in[26];
  const float* gamma = (const float*)d_in[27];
  float* OUT = (float*)d_out;

  const size_t FIELD = (size_t)NB * HGT * WID * CH;
  bf* Ql = (bf*)d_ws;
  bf* Qr = Ql + FIELD;
  bf* Vl = Qr + FIELD;     // after k_attn: holds F_l2r
  bf* Vr = Vl + FIELD;     // after k_attn: holds F_r2l
  bf* Wcat = Vr + FIELD;
  float* bv = (float*)(Wcat + 96*384);
  bf* Cq = (bf*)d_out;     // conv1x1 intermediates alias d_out
  bf* Cv = Cq + FIELD;

  dim3 blk(256,1,1);
  k_wprep<<<dim3(96,1,1), blk, 0, stream>>>(lp2_w, lp2_b, rp2_w, rp2_b,
        down_w, down_b, beta, gamma, Wcat, bv);
  k_c1x1<<<dim3(2048,1,1), blk, 0, stream>>>(I1, se1_w, se1_b, lp1_w, lp1_b, Cq, Cv);
  k_dw  <<<dim3(4,52,16),  blk, 0, stream>>>(Cq, Cv, se1_dw, se1_db, lp1_dw, lp1_db, Ql, Vl);
  k_c1x1<<<dim3(2048,1,1), blk, 0, stream>>>(I2, se2_w, se2_b, rp1_w, rp1_b, Cq, Cv);
  k_dw  <<<dim3(4,52,16),  blk, 0, stream>>>(Cq, Cv, se2_dw, se2_db, rp1_dw, rp1_db, Qr, Vr);
  k_attn<<<dim3(NB*HGT,1,1), blk, 96*264*2 + 256*4, stream>>>(Ql, Qr, Vl, Vr);
  k_fuse<<<dim3(4096,1,1), blk, 0, stream>>>(I1, I2, Vr, Vl, Wcat, bv, OUT);
}

// Round 15
// 946.301 us; speedup vs baseline: 1.0102x; 1.0102x over previous
//
#include <hip/hip_runtime.h>
#include <hip/hip_bf16.h>
#include <stdint.h>

typedef __bf16 bf;
typedef __bf16 bfv8 __attribute__((ext_vector_type(8)));
typedef __bf16 bfv4 __attribute__((ext_vector_type(4)));
typedef float  f32x4 __attribute__((ext_vector_type(4)));

#define MFMA16(a,b,c) __builtin_amdgcn_mfma_f32_16x16x32_bf16((a),(b),(c),0,0,0)

#define CH  96
#define WID 256
#define HGT 256
#define NB  8
#define SCALE 0.1020620726159658f   // 96^-0.5

__device__ __forceinline__ float b2f(bf x){ return (float)x; }
__device__ __forceinline__ bf   f2b(float x){ return (bf)x; }

__device__ __forceinline__ bfv8 ld_cvt8(const float* __restrict__ p){
  f32x4 a = *(const f32x4*)p;
  f32x4 b = *(const f32x4*)(p + 4);
  bfv8 r;
  r[0]=f2b(a[0]); r[1]=f2b(a[1]); r[2]=f2b(a[2]); r[3]=f2b(a[3]);
  r[4]=f2b(b[0]); r[5]=f2b(b[1]); r[6]=f2b(b[2]); r[7]=f2b(b[3]);
  return r;
}
__device__ __forceinline__ bfv4 pack4(float a,float b,float c,float d){
  bfv4 r; r[0]=f2b(a); r[1]=f2b(b); r[2]=f2b(c); r[3]=f2b(d); return r;
}

// ---------------- K_c1x1: conv1x1 GEMM, LDS-resident weights (low VGPR), prefetch ----------------
__global__ __launch_bounds__(256) void k_c1x1(
    const float* __restrict__ X,
    const float* __restrict__ Wa, const float* __restrict__ Ba,
    const float* __restrict__ Wb, const float* __restrict__ Bb,
    bf* __restrict__ Ca, bf* __restrict__ Cb)
{
  __shared__ bf wlds0[96*96];
  __shared__ bf wlds1[96*96];
  __shared__ float blds[2][96];
  const int tid=threadIdx.x, lane=tid&63, wv=tid>>6;
  const int l15=lane&15, lg=lane>>4;

  for (int k = tid; k < (96*96)/8; k += 256){
    ((bfv8*)wlds0)[k] = ld_cvt8(Wa + k*8);
    ((bfv8*)wlds1)[k] = ld_cvt8(Wb + k*8);
  }
  if (tid < 96){ blds[0][tid] = Ba[tid]; blds[1][tid] = Bb[tid]; }
  __syncthreads();

  const int set = wv&1, th = wv>>1;
  const bf* W1 = set ? wlds1 : wlds0;
  const float* B1 = blds[set];
  bf* C = set ? Cb : Ca;
  const size_t p0 = (size_t)blockIdx.x * 256;
  const int t0 = th*8;

  f32x4 bias4[6];
#pragma unroll
  for (int nt=0;nt<6;++nt)
    bias4[nt] = *(const f32x4*)(B1 + nt*16 + lg*4);

  bfv8 af[3], afn[3];
#pragma unroll
  for (int ks=0;ks<3;++ks)
    af[ks] = ld_cvt8(X + (p0 + t0*16 + l15)*CH + ks*32 + lg*8);

#pragma unroll 1
  for (int i=0;i<8;++i){
    const int m0 = (t0+i)*16;
    if (i<7){
#pragma unroll
      for (int ks=0;ks<3;++ks)
        afn[ks] = ld_cvt8(X + (p0+m0+16+l15)*CH + ks*32 + lg*8);
    }
    f32x4 acc[6];
#pragma unroll
    for (int nt=0;nt<6;++nt) acc[nt]=bias4[nt];
#pragma unroll
    for (int ks=0;ks<3;++ks)
#pragma unroll
      for (int nt=0;nt<6;++nt)
        acc[nt] = MFMA16(*(const bfv8*)(W1 + (nt*16+l15)*CH + ks*32 + lg*8),
                         af[ks], acc[nt]);   // A=W (LDS), B=X
#pragma unroll
    for (int nt=0;nt<6;++nt)
      *(bfv4*)(C + (p0+m0+l15)*CH + nt*16 + lg*4)
        = pack4(acc[nt][0],acc[nt][1],acc[nt][2],acc[nt][3]);
#pragma unroll
    for (int ks=0;ks<3;++ks) af[ks]=afn[ks];
  }
}

// ---------------- K_dw: depthwise 3x3, 2-column-deep software pipeline ----------------
__global__ __launch_bounds__(256) void k_dw(
    const bf* __restrict__ C0, const bf* __restrict__ C1,
    const float* __restrict__ WD0, const float* __restrict__ BD0,
    const float* __restrict__ WD1, const float* __restrict__ BD1,
    bf* __restrict__ O0, bf* __restrict__ O1)
{
  const int tid = threadIdx.x;
  if (tid >= 240) return;
  const int g = tid % 12, slot = tid / 12;
  const int yrow = slot >> 2, xrun = slot & 3;
  const int b = blockIdx.z >> 1, s = blockIdx.z & 1;
  const bf* C = s ? C1 : C0;
  const float* WD = s ? WD1 : WD0;
  const float* BD = s ? BD1 : BD0;
  bf* O = s ? O1 : O0;
  const int x0 = blockIdx.x*64 + xrun*16;
  const int y  = blockIdx.y*5 + yrow;
  if (y >= HGT) return;
  const size_t ib = (size_t)b * (HGT*WID) * CH;

  float wv[9][8], bb[8];
#pragma unroll
  for (int j=0;j<8;++j){
    bb[j] = BD[g*8+j];
#pragma unroll
    for (int t=0;t<9;++t) wv[t][j] = WD[(g*8+j)*9 + t];
  }

  const bf* r0 = C + ib + ((size_t)(y-1)*WID)*CH + g*8;
  const bf* r1 = C + ib + ((size_t)(y  )*WID)*CH + g*8;
  const bf* r2 = C + ib + ((size_t)(y+1)*WID)*CH + g*8;
  const bool v0 = (y > 0), v2 = (y+1 < HGT);
  const bfv8 Z = {0,0,0,0,0,0,0,0};

  bfv8 w00,w01,w02, w10,w11,w12, w20,w21,w22;
  bfv8 na0,na1,na2, nb0,nb1,nb2;
  {
    bool vx = (x0 > 0);
    size_t o = (size_t)(x0-1)*CH;
    w00 = (v0&&vx) ? *(const bfv8*)(r0+o) : Z;
    w10 = vx       ? *(const bfv8*)(r1+o) : Z;
    w20 = (v2&&vx) ? *(const bfv8*)(r2+o) : Z;
  }
  {
    size_t o = (size_t)x0*CH;
    w01 = v0 ? *(const bfv8*)(r0+o) : Z;
    w11 =      *(const bfv8*)(r1+o);
    w21 = v2 ? *(const bfv8*)(r2+o) : Z;
  }
  {
    int xn = x0+1; bool vx = (xn < WID);
    size_t o = (size_t)xn*CH;
    na0 = (v0&&vx) ? *(const bfv8*)(r0+o) : Z;
    na1 = vx       ? *(const bfv8*)(r1+o) : Z;
    na2 = (v2&&vx) ? *(const bfv8*)(r2+o) : Z;
  }
  {
    int xn = x0+2; bool vx = (xn < WID);
    size_t o = (size_t)xn*CH;
    nb0 = (v0&&vx) ? *(const bfv8*)(r0+o) : Z;
    nb1 = vx       ? *(const bfv8*)(r1+o) : Z;
    nb2 = (v2&&vx) ? *(const bfv8*)(r2+o) : Z;
  }
#pragma unroll
  for (int xi=0; xi<16; ++xi){
    w02 = na0; w12 = na1; w22 = na2;
    na0 = nb0; na1 = nb1; na2 = nb2;
    {
      int xn = x0 + xi + 3;
      bool vx = (xn < WID) && (xi < 14);
      size_t o = (size_t)xn*CH;
      nb0 = (v0&&vx) ? *(const bfv8*)(r0+o) : Z;
      nb1 = vx       ? *(const bfv8*)(r1+o) : Z;
      nb2 = (v2&&vx) ? *(const bfv8*)(r2+o) : Z;
    }
    float acc[8];
#pragma unroll
    for (int j=0;j<8;++j) acc[j] = bb[j];
#pragma unroll
    for (int j=0;j<8;++j){
      acc[j] += wv[0][j]*b2f(w00[j]);
      acc[j] += wv[1][j]*b2f(w01[j]);
      acc[j] += wv[2][j]*b2f(w02[j]);
      acc[j] += wv[3][j]*b2f(w10[j]);
      acc[j] += wv[4][j]*b2f(w11[j]);
      acc[j] += wv[5][j]*b2f(w12[j]);
      acc[j] += wv[6][j]*b2f(w20[j]);
      acc[j] += wv[7][j]*b2f(w21[j]);
      acc[j] += wv[8][j]*b2f(w22[j]);
    }
    bfv8 st;
#pragma unroll
    for (int j=0;j<8;++j) st[j] = f2b(acc[j]);
    *(bfv8*)(O + ib + ((size_t)y*WID + x0 + xi)*CH + g*8) = st;
    w00=w01; w01=w02;
    w10=w11; w11=w12;
    w20=w21; w21=w22;
  }
}

// ---------------- K_attn v5 (reverted): F written into the dead V buffers (ws) ----------------
__global__ __launch_bounds__(256) void k_attn(
    const bf* __restrict__ Ql, const bf* __restrict__ Qr,
    bf* Vl, bf* Vr)
{
  extern __shared__ char sm[];
  bf* vt = (bf*)sm;                          // [96][264] = 50,688 B
  bf* aq = (bf*)(sm + 96*264*2);             // 4 x [16][104] = 13,312 B
  float* rs = (float*)(sm + 96*264*2 + 4*16*104*2);  // [256]
  const int tid=threadIdx.x, lane=tid&63, wid=tid>>6;
  const int l15=lane&15, lg=lane>>4;
  bf* aqw = aq + wid*(16*104);
  const int bh = blockIdx.x;
  const size_t qoff = (size_t)bh * (WID*CH);

#pragma unroll 1
  for (int phase=0; phase<2; ++phase) {
    const bf* msrc = phase ? Qr+qoff : Ql+qoff;
    const bf* nsrc = phase ? Ql+qoff : Qr+qoff;
    bf* Vp = (phase ? Vl : Vr) + qoff;
    if (phase) {
      __syncthreads();
      rs[tid] = SCALE / rs[tid];
    }
    {
      const bfv8* src = (const bfv8*)(Vp + (size_t)tid*CH);
#pragma unroll
      for (int i=0;i<12;++i){
        bfv8 v8 = src[i];
#pragma unroll
        for (int j=0;j<8;++j) vt[(i*8+j)*264 + tid] = v8[j];
      }
    }
    __syncthreads();

#pragma unroll 1
    for (int qp=0; qp<2; ++qp){
      bfv8 af2[2][3];
#pragma unroll
      for (int q01=0;q01<2;++q01){
        const int m0 = (qp*2+q01)*64 + wid*16;
#pragma unroll
        for (int ks=0;ks<3;++ks)
          af2[q01][ks] = *(const bfv8*)(msrc + (size_t)(m0+l15)*CH + ks*32 + lg*8);
      }
      f32x4 o[2][6];
#pragma unroll
      for (int q01=0;q01<2;++q01)
#pragma unroll
        for (int nt=0;nt<6;++nt) o[q01][nt]=(f32x4){0.f,0.f,0.f,0.f};
      float rsum2[2]={0.f,0.f};

#pragma unroll 1
      for (int c4=0;c4<4;++c4){
        bfv8 nb[4][3];
#pragma unroll
        for (int nt=0;nt<4;++nt)
#pragma unroll
          for (int ks=0;ks<3;++ks)
            nb[nt][ks] = *(const bfv8*)(nsrc + (size_t)(c4*64+nt*16+l15)*CH + ks*32+lg*8);
        f32x4 fwv4[4];
        if (phase){
#pragma unroll
          for (int nt=0;nt<4;++nt)
            fwv4[nt] = *(const f32x4*)(rs + c4*64 + nt*16 + lg*4);
        }
#pragma unroll
        for (int q01=0;q01<2;++q01){
          f32x4 acc[4];
#pragma unroll
          for (int nt=0;nt<4;++nt) acc[nt]=(f32x4){0.f,0.f,0.f,0.f};
#pragma unroll
          for (int ks=0;ks<3;++ks)
#pragma unroll
            for (int nt=0;nt<4;++nt)
              acc[nt]=MFMA16(nb[nt][ks], af2[q01][ks], acc[nt]);
          if (phase==0){
#pragma unroll
            for (int nt=0;nt<4;++nt){
              float e0=__expf(acc[nt][0]), e1=__expf(acc[nt][1]);
              float e2=__expf(acc[nt][2]), e3=__expf(acc[nt][3]);
              rsum2[q01] += (e0+e1)+(e2+e3);
              *(bfv4*)(aqw + l15*104 + nt*16 + lg*4) = pack4(e0,e1,e2,e3);
            }
          } else {
#pragma unroll
            for (int nt=0;nt<4;++nt){
              float e0=__expf(acc[nt][0])*fwv4[nt][0];
              float e1=__expf(acc[nt][1])*fwv4[nt][1];
              float e2=__expf(acc[nt][2])*fwv4[nt][2];
              float e3=__expf(acc[nt][3])*fwv4[nt][3];
              *(bfv4*)(aqw + l15*104 + nt*16 + lg*4) = pack4(e0,e1,e2,e3);
            }
          }
#pragma unroll
          for (int ks=0;ks<2;++ks){
            bfv8 aa = *(const bfv8*)(aqw + l15*104 + ks*32 + lg*8);
#pragma unroll
            for (int nt=0;nt<6;++nt)
              o[q01][nt]=MFMA16(
                *(const bfv8*)(vt + (nt*16+l15)*264 + c4*64 + ks*32 + lg*8),
                aa, o[q01][nt]);
          }
        }
      }
#pragma unroll
      for (int q01=0;q01<2;++q01){
        const int m0 = (qp*2+q01)*64 + wid*16;
        float sc;
        if (phase==0){
          float rsv = rsum2[q01];
          rsv += __shfl_xor(rsv, 16, 64);
          rsv += __shfl_xor(rsv, 32, 64);
          if (lane < 16) rs[m0 + l15] = rsv;
          sc = SCALE / rsv;
        } else sc = 1.f;
#pragma unroll
        for (int nt=0;nt<6;++nt)
          *(bfv4*)(aqw + l15*104 + nt*16 + lg*4)
            = pack4(o[q01][nt][0]*sc, o[q01][nt][1]*sc,
                    o[q01][nt][2]*sc, o[q01][nt][3]*sc);
        const size_t pbase = (size_t)m0;
#pragma unroll
        for (int i=0;i<3;++i){
          int u=lane+64*i; int gr=u/12, sg=u%12;
          *(bfv8*)(Vp + (pbase+gr)*CH + sg*8)
            = *(const bfv8*)(aqw + gr*104 + sg*8);
        }
      }
    }
  }
}

// ---------------- K_wprep ----------------
__global__ __launch_bounds__(256) void k_wprep(
    const float* __restrict__ L, const float* __restrict__ lb,
    const float* __restrict__ R, const float* __restrict__ rb,
    const float* __restrict__ D, const float* __restrict__ db,
    const float* __restrict__ beta, const float* __restrict__ gamma,
    bf* __restrict__ Wcat, float* __restrict__ bv)
{
  const int o = blockIdx.x;
  const int tid = threadIdx.x;
  for (int k = tid; k < 384; k += 256){
    float v;
    if (k < 192) v = D[o*192 + k];
    else if (k < 288){
      int c = k - 192; float s = 0.f;
      for (int m=0;m<96;++m) s += D[o*192+m]*beta[m]*L[m*96+c];
      v = s;
    } else {
      int c = k - 288; float s = 0.f;
      for (int m=0;m<96;++m) s += D[o*192+96+m]*gamma[m]*R[m*96+c];
      v = s;
    }
    Wcat[o*384+k] = f2b(v);
  }
  if (tid == 0){
    float s = db[o];
    for (int m=0;m<96;++m) s += D[o*192+m]*beta[m]*lb[m] + D[o*192+96+m]*gamma[m]*rb[m];
    bv[o] = s;
  }
}

// ---------------- K_fuse v5: F-part weights in LDS (low VGPR), x-part in regs ----------------
// LDS wl[96][200] = 38,400 B (pad 8 -> 2-way banks). VGPR ~ -72 vs v4 -> more waves in flight.
__global__ __launch_bounds__(256) void k_fuse(
    const float* __restrict__ I1, const float* __restrict__ I2,
    const bf* __restrict__ F1, const bf* __restrict__ F2,
    const bf* __restrict__ Wcat, const float* __restrict__ bv,
    float* __restrict__ OUT)
{
  __shared__ bf wl[96*200];
  const int tid=threadIdx.x, lane=tid&63, wv=tid>>6;
  const int l15=lane&15, lg=lane>>4;
  const int half = wv&1, pair = wv>>1;
  const size_t p0 = (size_t)blockIdx.x * 128;

  { // stage F-part weights (Wcat cols 192..383) -> LDS [96][200]
    for (int k = tid; k < 96*24; k += 256){
      int c = k / 24, seg = k % 24;
      *(bfv8*)(wl + c*200 + seg*8) = *(const bfv8*)(Wcat + (size_t)c*384 + 192 + seg*8);
    }
  }

  bfv8 wfx[6][3];          // x-part weights (k=0..191) in registers
  f32x4 bias4[3];
#pragma unroll
  for (int j=0;j<3;++j){
    int c = (half*3+j)*16;
    bias4[j] = *(const f32x4*)(bv + c + lg*4);
#pragma unroll
    for (int kb=0;kb<6;++kb)
      wfx[kb][j] = *(const bfv8*)(Wcat + (size_t)(c+l15)*384 + kb*32 + lg*8);
  }
  __syncthreads();

  bfv8 a[12], an[12];
  {
    const size_t m0 = p0 + pair*4*16;
    const float* x1 = I1 + (m0+l15)*CH + lg*8;
    const float* x2 = I2 + (m0+l15)*CH + lg*8;
    const bf* f1 = F1 + (m0+l15)*CH + lg*8;
    const bf* f2 = F2 + (m0+l15)*CH + lg*8;
#pragma unroll
    for (int ks=0;ks<3;++ks){
      a[ks]   = ld_cvt8(x1 + ks*32);
      a[3+ks] = ld_cvt8(x2 + ks*32);
      a[6+ks] = *(const bfv8*)(f1 + ks*32);
      a[9+ks] = *(const bfv8*)(f2 + ks*32);
    }
  }
#pragma unroll 1
  for (int i=0;i<4;++i){
    const size_t m0 = p0 + (pair*4+i)*16;
    if (i<3){
      const size_t mn = m0 + 16;
      const float* x1 = I1 + (mn+l15)*CH + lg*8;
      const float* x2 = I2 + (mn+l15)*CH + lg*8;
      const bf* f1 = F1 + (mn+l15)*CH + lg*8;
      const bf* f2 = F2 + (mn+l15)*CH + lg*8;
#pragma unroll
      for (int ks=0;ks<3;++ks){
        an[ks]   = ld_cvt8(x1 + ks*32);
        an[3+ks] = ld_cvt8(x2 + ks*32);
        an[6+ks] = *(const bfv8*)(f1 + ks*32);
        an[9+ks] = *(const bfv8*)(f2 + ks*32);
      }
    }
    f32x4 acc[3];
#pragma unroll
    for (int j=0;j<3;++j) acc[j]=bias4[j];
#pragma unroll
    for (int kb=0;kb<6;++kb)
#pragma unroll
      for (int j=0;j<3;++j)
        acc[j] = MFMA16(wfx[kb][j], a[kb], acc[j]);        // x-part, reg weights
#pragma unroll
    for (int kb=6;kb<12;++kb)
#pragma unroll
      for (int j=0;j<3;++j)
        acc[j] = MFMA16(
          *(const bfv8*)(wl + (size_t)((half*3+j)*16+l15)*200 + (kb-6)*32 + lg*8),
          a[kb], acc[j]);                                   // F-part, LDS weights
#pragma unroll
    for (int j=0;j<3;++j)
      *(f32x4*)(OUT + (m0+l15)*CH + (half*3+j)*16 + lg*4) = acc[j];
#pragma unroll
    for (int kb=0;kb<12;++kb) a[kb]=an[kb];
  }
}

extern "C" void kernel_launch(void* const* d_in, const int* in_sizes, int n_in,
                              void* d_out, int out_size, void* d_ws, size_t ws_size,
                              hipStream_t stream)
{
  (void)in_sizes; (void)n_in; (void)out_size; (void)ws_size;
  const float* I1 = (const float*)d_in[0];
  const float* I2 = (const float*)d_in[1];
  const float* se1_w = (const float*)d_in[4];
  const float* se1_b = (const float*)d_in[5];
  const float* se1_dw= (const float*)d_in[6];
  const float* se1_db= (const float*)d_in[7];
  const float* se2_w = (const float*)d_in[8];
  const float* se2_b = (const float*)d_in[9];
  const float* se2_dw= (const float*)d_in[10];
  const float* se2_db= (const float*)d_in[11];
  const float* lp1_w = (const float*)d_in[12];
  const float* lp1_b = (const float*)d_in[13];
  const float* lp1_dw= (const float*)d_in[14];
  const float* lp1_db= (const float*)d_in[15];
  const float* rp1_w = (const float*)d_in[16];
  const float* rp1_b = (const float*)d_in[17];
  const float* rp1_dw= (const float*)d_in[18];
  const float* rp1_db= (const float*)d_in[19];
  const float* lp2_w = (const float*)d_in[20];
  const float* lp2_b = (const float*)d_in[21];
  const float* rp2_w = (const float*)d_in[22];
  const float* rp2_b = (const float*)d_in[23];
  const float* down_w= (const float*)d_in[24];
  const float* down_b= (const float*)d_in[25];
  const float* beta  = (const float*)d_in[26];
  const float* gamma = (const float*)d_in[27];
  float* OUT = (float*)d_out;

  const size_t FIELD = (size_t)NB * HGT * WID * CH;
  bf* Ql = (bf*)d_ws;
  bf* Qr = Ql + FIELD;
  bf* Vl = Qr + FIELD;     // after k_attn: holds F_l2r
  bf* Vr = Vl + FIELD;     // after k_attn: holds F_r2l
  bf* Wcat = Vr + FIELD;
  float* bv = (float*)(Wcat + 96*384);
  bf* Cq = (bf*)d_out;     // conv1x1 intermediates alias d_out
  bf* Cv = Cq + FIELD;

  dim3 blk(256,1,1);
  k_wprep<<<dim3(96,1,1), blk, 0, stream>>>(lp2_w, lp2_b, rp2_w, rp2_b,
        down_w, down_b, beta, gamma, Wcat, bv);
  k_c1x1<<<dim3(2048,1,1), blk, 0, stream>>>(I1, se1_w, se1_b, lp1_w, lp1_b, Cq, Cv);
  k_dw  <<<dim3(4,52,16),  blk, 0, stream>>>(Cq, Cv, se1_dw, se1_db, lp1_dw, lp1_db, Ql, Vl);
  k_c1x1<<<dim3(2048,1,1), blk, 0, stream>>>(I2, se2_w, se2_b, rp1_w, rp1_b, Cq, Cv);
  k_dw  <<<dim3(4,52,16),  blk, 0, stream>>>(Cq, Cv, se2_dw, se2_db, rp1_dw, rp1_db, Qr, Vr);
  k_attn<<<dim3(NB*HGT,1,1), blk, 96*264*2 + 4*16*104*2 + 256*4, stream>>>(Ql, Qr, Vl, Vr);
  k_fuse<<<dim3(4096,1,1), blk, 0, stream>>>(I1, I2, Vr, Vl, Wcat, bv, OUT);
}

// Round 16
// 904.259 us; speedup vs baseline: 1.0572x; 1.0465x over previous
//
#include <hip/hip_runtime.h>
#include <hip/hip_bf16.h>
#include <stdint.h>

typedef __bf16 bf;
typedef __bf16 bfv8 __attribute__((ext_vector_type(8)));
typedef __bf16 bfv4 __attribute__((ext_vector_type(4)));
typedef float  f32x4 __attribute__((ext_vector_type(4)));

#define MFMA16(a,b,c) __builtin_amdgcn_mfma_f32_16x16x32_bf16((a),(b),(c),0,0,0)

#define CH  96
#define WID 256
#define HGT 256
#define NB  8
#define SCALE 0.1020620726159658f   // 96^-0.5

__device__ __forceinline__ float b2f(bf x){ return (float)x; }
__device__ __forceinline__ bf   f2b(float x){ return (bf)x; }

__device__ __forceinline__ bfv8 ld_cvt8(const float* __restrict__ p){
  f32x4 a = *(const f32x4*)p;
  f32x4 b = *(const f32x4*)(p + 4);
  bfv8 r;
  r[0]=f2b(a[0]); r[1]=f2b(a[1]); r[2]=f2b(a[2]); r[3]=f2b(a[3]);
  r[4]=f2b(b[0]); r[5]=f2b(b[1]); r[6]=f2b(b[2]); r[7]=f2b(b[3]);
  return r;
}
__device__ __forceinline__ bfv4 pack4(float a,float b,float c,float d){
  bfv4 r; r[0]=f2b(a); r[1]=f2b(b); r[2]=f2b(c); r[3]=f2b(d); return r;
}

// ---------------- K_c1x1 v3: LDS weights + grid-stride 512 px/block ----------------
// Weight staging (36.9KB) amortized over 16 tile-iterations; grid 1024 = resident capacity.
__global__ __launch_bounds__(256) void k_c1x1(
    const float* __restrict__ X,
    const float* __restrict__ Wa, const float* __restrict__ Ba,
    const float* __restrict__ Wb, const float* __restrict__ Bb,
    bf* __restrict__ Ca, bf* __restrict__ Cb)
{
  __shared__ bf wlds0[96*96];
  __shared__ bf wlds1[96*96];
  __shared__ float blds[2][96];
  const int tid=threadIdx.x, lane=tid&63, wv=tid>>6;
  const int l15=lane&15, lg=lane>>4;

  for (int k = tid; k < (96*96)/8; k += 256){
    ((bfv8*)wlds0)[k] = ld_cvt8(Wa + k*8);
    ((bfv8*)wlds1)[k] = ld_cvt8(Wb + k*8);
  }
  if (tid < 96){ blds[0][tid] = Ba[tid]; blds[1][tid] = Bb[tid]; }
  __syncthreads();

  const int set = wv&1, th = wv>>1;
  const bf* W1 = set ? wlds1 : wlds0;
  const float* B1 = blds[set];
  bf* C = set ? Cb : Ca;
  const size_t p0 = (size_t)blockIdx.x * 512;

  f32x4 bias4[6];
#pragma unroll
  for (int nt=0;nt<6;++nt)
    bias4[nt] = *(const f32x4*)(B1 + nt*16 + lg*4);

  // tile t in 0..15: chunk c=t>>3 (256px), tile (th*8 + (t&7))*16 within chunk
  auto mof = [&](int t)->int{ return (t>>3)*256 + (th*8 + (t&7))*16; };

  bfv8 af[3], afn[3];
#pragma unroll
  for (int ks=0;ks<3;++ks)
    af[ks] = ld_cvt8(X + (p0 + mof(0) + l15)*CH + ks*32 + lg*8);

#pragma unroll 1
  for (int t=0;t<16;++t){
    const int m0 = mof(t);
    if (t<15){
      const int mn = mof(t+1);
#pragma unroll
      for (int ks=0;ks<3;++ks)
        afn[ks] = ld_cvt8(X + (p0+mn+l15)*CH + ks*32 + lg*8);
    }
    f32x4 acc[6];
#pragma unroll
    for (int nt=0;nt<6;++nt) acc[nt]=bias4[nt];
#pragma unroll
    for (int ks=0;ks<3;++ks)
#pragma unroll
      for (int nt=0;nt<6;++nt)
        acc[nt] = MFMA16(*(const bfv8*)(W1 + (nt*16+l15)*CH + ks*32 + lg*8),
                         af[ks], acc[nt]);   // A=W (LDS), B=X
#pragma unroll
    for (int nt=0;nt<6;++nt)
      *(bfv4*)(C + (p0+m0+l15)*CH + nt*16 + lg*4)
        = pack4(acc[nt][0],acc[nt][1],acc[nt][2],acc[nt][3]);
#pragma unroll
    for (int ks=0;ks<3;++ks) af[ks]=afn[ks];
  }
}

// ---------------- K_dw: depthwise 3x3, 2-column-deep software pipeline ----------------
__global__ __launch_bounds__(256) void k_dw(
    const bf* __restrict__ C0, const bf* __restrict__ C1,
    const float* __restrict__ WD0, const float* __restrict__ BD0,
    const float* __restrict__ WD1, const float* __restrict__ BD1,
    bf* __restrict__ O0, bf* __restrict__ O1)
{
  const int tid = threadIdx.x;
  if (tid >= 240) return;
  const int g = tid % 12, slot = tid / 12;
  const int yrow = slot >> 2, xrun = slot & 3;
  const int b = blockIdx.z >> 1, s = blockIdx.z & 1;
  const bf* C = s ? C1 : C0;
  const float* WD = s ? WD1 : WD0;
  const float* BD = s ? BD1 : BD0;
  bf* O = s ? O1 : O0;
  const int x0 = blockIdx.x*64 + xrun*16;
  const int y  = blockIdx.y*5 + yrow;
  if (y >= HGT) return;
  const size_t ib = (size_t)b * (HGT*WID) * CH;

  float wv[9][8], bb[8];
#pragma unroll
  for (int j=0;j<8;++j){
    bb[j] = BD[g*8+j];
#pragma unroll
    for (int t=0;t<9;++t) wv[t][j] = WD[(g*8+j)*9 + t];
  }

  const bf* r0 = C + ib + ((size_t)(y-1)*WID)*CH + g*8;
  const bf* r1 = C + ib + ((size_t)(y  )*WID)*CH + g*8;
  const bf* r2 = C + ib + ((size_t)(y+1)*WID)*CH + g*8;
  const bool v0 = (y > 0), v2 = (y+1 < HGT);
  const bfv8 Z = {0,0,0,0,0,0,0,0};

  bfv8 w00,w01,w02, w10,w11,w12, w20,w21,w22;
  bfv8 na0,na1,na2, nb0,nb1,nb2;
  {
    bool vx = (x0 > 0);
    size_t o = (size_t)(x0-1)*CH;
    w00 = (v0&&vx) ? *(const bfv8*)(r0+o) : Z;
    w10 = vx       ? *(const bfv8*)(r1+o) : Z;
    w20 = (v2&&vx) ? *(const bfv8*)(r2+o) : Z;
  }
  {
    size_t o = (size_t)x0*CH;
    w01 = v0 ? *(const bfv8*)(r0+o) : Z;
    w11 =      *(const bfv8*)(r1+o);
    w21 = v2 ? *(const bfv8*)(r2+o) : Z;
  }
  {
    int xn = x0+1; bool vx = (xn < WID);
    size_t o = (size_t)xn*CH;
    na0 = (v0&&vx) ? *(const bfv8*)(r0+o) : Z;
    na1 = vx       ? *(const bfv8*)(r1+o) : Z;
    na2 = (v2&&vx) ? *(const bfv8*)(r2+o) : Z;
  }
  {
    int xn = x0+2; bool vx = (xn < WID);
    size_t o = (size_t)xn*CH;
    nb0 = (v0&&vx) ? *(const bfv8*)(r0+o) : Z;
    nb1 = vx       ? *(const bfv8*)(r1+o) : Z;
    nb2 = (v2&&vx) ? *(const bfv8*)(r2+o) : Z;
  }
#pragma unroll
  for (int xi=0; xi<16; ++xi){
    w02 = na0; w12 = na1; w22 = na2;
    na0 = nb0; na1 = nb1; na2 = nb2;
    {
      int xn = x0 + xi + 3;
      bool vx = (xn < WID) && (xi < 14);
      size_t o = (size_t)xn*CH;
      nb0 = (v0&&vx) ? *(const bfv8*)(r0+o) : Z;
      nb1 = vx       ? *(const bfv8*)(r1+o) : Z;
      nb2 = (v2&&vx) ? *(const bfv8*)(r2+o) : Z;
    }
    float acc[8];
#pragma unroll
    for (int j=0;j<8;++j) acc[j] = bb[j];
#pragma unroll
    for (int j=0;j<8;++j){
      acc[j] += wv[0][j]*b2f(w00[j]);
      acc[j] += wv[1][j]*b2f(w01[j]);
      acc[j] += wv[2][j]*b2f(w02[j]);
      acc[j] += wv[3][j]*b2f(w10[j]);
      acc[j] += wv[4][j]*b2f(w11[j]);
      acc[j] += wv[5][j]*b2f(w12[j]);
      acc[j] += wv[6][j]*b2f(w20[j]);
      acc[j] += wv[7][j]*b2f(w21[j]);
      acc[j] += wv[8][j]*b2f(w22[j]);
    }
    bfv8 st;
#pragma unroll
    for (int j=0;j<8;++j) st[j] = f2b(acc[j]);
    *(bfv8*)(O + ib + ((size_t)y*WID + x0 + xi)*CH + g*8) = st;
    w00=w01; w01=w02;
    w10=w11; w11=w12;
    w20=w21; w21=w22;
  }
}

// ---------------- K_attn v5: F written into the dead V buffers (ws) ----------------
__global__ __launch_bounds__(256) void k_attn(
    const bf* __restrict__ Ql, const bf* __restrict__ Qr,
    bf* Vl, bf* Vr)
{
  extern __shared__ char sm[];
  bf* vt = (bf*)sm;                          // [96][264] = 50,688 B
  bf* aq = (bf*)(sm + 96*264*2);             // 4 x [16][104] = 13,312 B
  float* rs = (float*)(sm + 96*264*2 + 4*16*104*2);  // [256]
  const int tid=threadIdx.x, lane=tid&63, wid=tid>>6;
  const int l15=lane&15, lg=lane>>4;
  bf* aqw = aq + wid*(16*104);
  const int bh = blockIdx.x;
  const size_t qoff = (size_t)bh * (WID*CH);

#pragma unroll 1
  for (int phase=0; phase<2; ++phase) {
    const bf* msrc = phase ? Qr+qoff : Ql+qoff;
    const bf* nsrc = phase ? Ql+qoff : Qr+qoff;
    bf* Vp = (phase ? Vl : Vr) + qoff;
    if (phase) {
      __syncthreads();
      rs[tid] = SCALE / rs[tid];
    }
    {
      const bfv8* src = (const bfv8*)(Vp + (size_t)tid*CH);
#pragma unroll
      for (int i=0;i<12;++i){
        bfv8 v8 = src[i];
#pragma unroll
        for (int j=0;j<8;++j) vt[(i*8+j)*264 + tid] = v8[j];
      }
    }
    __syncthreads();

#pragma unroll 1
    for (int qp=0; qp<2; ++qp){
      bfv8 af2[2][3];
#pragma unroll
      for (int q01=0;q01<2;++q01){
        const int m0 = (qp*2+q01)*64 + wid*16;
#pragma unroll
        for (int ks=0;ks<3;++ks)
          af2[q01][ks] = *(const bfv8*)(msrc + (size_t)(m0+l15)*CH + ks*32 + lg*8);
      }
      f32x4 o[2][6];
#pragma unroll
      for (int q01=0;q01<2;++q01)
#pragma unroll
        for (int nt=0;nt<6;++nt) o[q01][nt]=(f32x4){0.f,0.f,0.f,0.f};
      float rsum2[2]={0.f,0.f};

#pragma unroll 1
      for (int c4=0;c4<4;++c4){
        bfv8 nb[4][3];
#pragma unroll
        for (int nt=0;nt<4;++nt)
#pragma unroll
          for (int ks=0;ks<3;++ks)
            nb[nt][ks] = *(const bfv8*)(nsrc + (size_t)(c4*64+nt*16+l15)*CH + ks*32+lg*8);
        f32x4 fwv4[4];
        if (phase){
#pragma unroll
          for (int nt=0;nt<4;++nt)
            fwv4[nt] = *(const f32x4*)(rs + c4*64 + nt*16 + lg*4);
        }
#pragma unroll
        for (int q01=0;q01<2;++q01){
          f32x4 acc[4];
#pragma unroll
          for (int nt=0;nt<4;++nt) acc[nt]=(f32x4){0.f,0.f,0.f,0.f};
#pragma unroll
          for (int ks=0;ks<3;++ks)
#pragma unroll
            for (int nt=0;nt<4;++nt)
              acc[nt]=MFMA16(nb[nt][ks], af2[q01][ks], acc[nt]);
          if (phase==0){
#pragma unroll
            for (int nt=0;nt<4;++nt){
              float e0=__expf(acc[nt][0]), e1=__expf(acc[nt][1]);
              float e2=__expf(acc[nt][2]), e3=__expf(acc[nt][3]);
              rsum2[q01] += (e0+e1)+(e2+e3);
              *(bfv4*)(aqw + l15*104 + nt*16 + lg*4) = pack4(e0,e1,e2,e3);
            }
          } else {
#pragma unroll
            for (int nt=0;nt<4;++nt){
              float e0=__expf(acc[nt][0])*fwv4[nt][0];
              float e1=__expf(acc[nt][1])*fwv4[nt][1];
              float e2=__expf(acc[nt][2])*fwv4[nt][2];
              float e3=__expf(acc[nt][3])*fwv4[nt][3];
              *(bfv4*)(aqw + l15*104 + nt*16 + lg*4) = pack4(e0,e1,e2,e3);
            }
          }
#pragma unroll
          for (int ks=0;ks<2;++ks){
            bfv8 aa = *(const bfv8*)(aqw + l15*104 + ks*32 + lg*8);
#pragma unroll
            for (int nt=0;nt<6;++nt)
              o[q01][nt]=MFMA16(
                *(const bfv8*)(vt + (nt*16+l15)*264 + c4*64 + ks*32 + lg*8),
                aa, o[q01][nt]);
          }
        }
      }
#pragma unroll
      for (int q01=0;q01<2;++q01){
        const int m0 = (qp*2+q01)*64 + wid*16;
        float sc;
        if (phase==0){
          float rsv = rsum2[q01];
          rsv += __shfl_xor(rsv, 16, 64);
          rsv += __shfl_xor(rsv, 32, 64);
          if (lane < 16) rs[m0 + l15] = rsv;
          sc = SCALE / rsv;
        } else sc = 1.f;
#pragma unroll
        for (int nt=0;nt<6;++nt)
          *(bfv4*)(aqw + l15*104 + nt*16 + lg*4)
            = pack4(o[q01][nt][0]*sc, o[q01][nt][1]*sc,
                    o[q01][nt][2]*sc, o[q01][nt][3]*sc);
        const size_t pbase = (size_t)m0;
#pragma unroll
        for (int i=0;i<3;++i){
          int u=lane+64*i; int gr=u/12, sg=u%12;
          *(bfv8*)(Vp + (pbase+gr)*CH + sg*8)
            = *(const bfv8*)(aqw + gr*104 + sg*8);
        }
      }
    }
  }
}

// ---------------- K_wprep ----------------
__global__ __launch_bounds__(256) void k_wprep(
    const float* __restrict__ L, const float* __restrict__ lb,
    const float* __restrict__ R, const float* __restrict__ rb,
    const float* __restrict__ D, const float* __restrict__ db,
    const float* __restrict__ beta, const float* __restrict__ gamma,
    bf* __restrict__ Wcat, float* __restrict__ bv)
{
  const int o = blockIdx.x;
  const int tid = threadIdx.x;
  for (int k = tid; k < 384; k += 256){
    float v;
    if (k < 192) v = D[o*192 + k];
    else if (k < 288){
      int c = k - 192; float s = 0.f;
      for (int m=0;m<96;++m) s += D[o*192+m]*beta[m]*L[m*96+c];
      v = s;
    } else {
      int c = k - 288; float s = 0.f;
      for (int m=0;m<96;++m) s += D[o*192+96+m]*gamma[m]*R[m*96+c];
      v = s;
    }
    Wcat[o*384+k] = f2b(v);
  }
  if (tid == 0){
    float s = db[o];
    for (int m=0;m<96;++m) s += D[o*192+m]*beta[m]*lb[m] + D[o*192+96+m]*gamma[m]*rb[m];
    bv[o] = s;
  }
}

// ---------------- K_fuse v6: grid-stride 512 px/block, F-weights LDS, prefetch ----------------
__global__ __launch_bounds__(256) void k_fuse(
    const float* __restrict__ I1, const float* __restrict__ I2,
    const bf* __restrict__ F1, const bf* __restrict__ F2,
    const bf* __restrict__ Wcat, const float* __restrict__ bv,
    float* __restrict__ OUT)
{
  __shared__ bf wl[96*200];
  const int tid=threadIdx.x, lane=tid&63, wv=tid>>6;
  const int l15=lane&15, lg=lane>>4;
  const int half = wv&1, pair = wv>>1;
  const size_t p0 = (size_t)blockIdx.x * 512;

  { // stage F-part weights (Wcat cols 192..383) -> LDS [96][200]
    for (int k = tid; k < 96*24; k += 256){
      int c = k / 24, seg = k % 24;
      *(bfv8*)(wl + c*200 + seg*8) = *(const bfv8*)(Wcat + (size_t)c*384 + 192 + seg*8);
    }
  }

  bfv8 wfx[6][3];          // x-part weights (k=0..191) in registers
  f32x4 bias4[3];
#pragma unroll
  for (int j=0;j<3;++j){
    int c = (half*3+j)*16;
    bias4[j] = *(const f32x4*)(bv + c + lg*4);
#pragma unroll
    for (int kb=0;kb<6;++kb)
      wfx[kb][j] = *(const bfv8*)(Wcat + (size_t)(c+l15)*384 + kb*32 + lg*8);
  }
  __syncthreads();

  // tile t in 0..15: m0 = p0 + (t>>2)*128 + pair*64 + (t&3)*16
  auto mof = [&](int t)->size_t{ return p0 + (size_t)((t>>2)*128 + pair*64 + (t&3)*16); };

  bfv8 a[12], an[12];
  {
    const size_t m0 = mof(0);
    const float* x1 = I1 + (m0+l15)*CH + lg*8;
    const float* x2 = I2 + (m0+l15)*CH + lg*8;
    const bf* f1 = F1 + (m0+l15)*CH + lg*8;
    const bf* f2 = F2 + (m0+l15)*CH + lg*8;
#pragma unroll
    for (int ks=0;ks<3;++ks){
      a[ks]   = ld_cvt8(x1 + ks*32);
      a[3+ks] = ld_cvt8(x2 + ks*32);
      a[6+ks] = *(const bfv8*)(f1 + ks*32);
      a[9+ks] = *(const bfv8*)(f2 + ks*32);
    }
  }
#pragma unroll 1
  for (int t=0;t<16;++t){
    const size_t m0 = mof(t);
    if (t<15){
      const size_t mn = mof(t+1);
      const float* x1 = I1 + (mn+l15)*CH + lg*8;
      const float* x2 = I2 + (mn+l15)*CH + lg*8;
      const bf* f1 = F1 + (mn+l15)*CH + lg*8;
      const bf* f2 = F2 + (mn+l15)*CH + lg*8;
#pragma unroll
      for (int ks=0;ks<3;++ks){
        an[ks]   = ld_cvt8(x1 + ks*32);
        an[3+ks] = ld_cvt8(x2 + ks*32);
        an[6+ks] = *(const bfv8*)(f1 + ks*32);
        an[9+ks] = *(const bfv8*)(f2 + ks*32);
      }
    }
    f32x4 acc[3];
#pragma unroll
    for (int j=0;j<3;++j) acc[j]=bias4[j];
#pragma unroll
    for (int kb=0;kb<6;++kb)
#pragma unroll
      for (int j=0;j<3;++j)
        acc[j] = MFMA16(wfx[kb][j], a[kb], acc[j]);        // x-part, reg weights
#pragma unroll
    for (int kb=6;kb<12;++kb)
#pragma unroll
      for (int j=0;j<3;++j)
        acc[j] = MFMA16(
          *(const bfv8*)(wl + (size_t)((half*3+j)*16+l15)*200 + (kb-6)*32 + lg*8),
          a[kb], acc[j]);                                   // F-part, LDS weights
#pragma unroll
    for (int j=0;j<3;++j)
      *(f32x4*)(OUT + (m0+l15)*CH + (half*3+j)*16 + lg*4) = acc[j];
#pragma unroll
    for (int kb=0;kb<12;++kb) a[kb]=an[kb];
  }
}

extern "C" void kernel_launch(void* const* d_in, const int* in_sizes, int n_in,
                              void* d_out, int out_size, void* d_ws, size_t ws_size,
                              hipStream_t stream)
{
  (void)in_sizes; (void)n_in; (void)out_size; (void)ws_size;
  const float* I1 = (const float*)d_in[0];
  const float* I2 = (const float*)d_in[1];
  const float* se1_w = (const float*)d_in[4];
  const float* se1_b = (const float*)d_in[5];
  const float* se1_dw= (const float*)d_in[6];
  const float* se1_db= (const float*)d_in[7];
  const float* se2_w = (const float*)d_in[8];
  const float* se2_b = (const float*)d_in[9];
  const float* se2_dw= (const float*)d_in[10];
  const float* se2_db= (const float*)d_in[11];
  const float* lp1_w = (const float*)d_in[12];
  const float* lp1_b = (const float*)d_in[13];
  const float* lp1_dw= (const float*)d_in[14];
  const float* lp1_db= (const float*)d_in[15];
  const float* rp1_w = (const float*)d_in[16];
  const float* rp1_b = (const float*)d_in[17];
  const float* rp1_dw= (const float*)d_in[18];
  const float* rp1_db= (const float*)d_in[19];
  const float* lp2_w = (const float*)d_in[20];
  const float* lp2_b = (const float*)d_in[21];
  const float* rp2_w = (const float*)d_in[22];
  const float* rp2_b = (const float*)d_in[23];
  const float* down_w= (const float*)d_in[24];
  const float* down_b= (const float*)d_in[25];
  const float* beta  = (const float*)d_in[26];
  const float* gamma = (const float*)d_in[27];
  float* OUT = (float*)d_out;

  const size_t FIELD = (size_t)NB * HGT * WID * CH;
  bf* Ql = (bf*)d_ws;
  bf* Qr = Ql + FIELD;
  bf* Vl = Qr + FIELD;     // after k_attn: holds F_l2r
  bf* Vr = Vl + FIELD;     // after k_attn: holds F_r2l
  bf* Wcat = Vr + FIELD;
  float* bv = (float*)(Wcat + 96*384);
  bf* Cq = (bf*)d_out;     // conv1x1 intermediates alias d_out
  bf* Cv = Cq + FIELD;

  dim3 blk(256,1,1);
  k_wprep<<<dim3(96,1,1), blk, 0, stream>>>(lp2_w, lp2_b, rp2_w, rp2_b,
        down_w, down_b, beta, gamma, Wcat, bv);
  k_c1x1<<<dim3(1024,1,1), blk, 0, stream>>>(I1, se1_w, se1_b, lp1_w, lp1_b, Cq, Cv);
  k_dw  <<<dim3(4,52,16),  blk, 0, stream>>>(Cq, Cv, se1_dw, se1_db, lp1_dw, lp1_db, Ql, Vl);
  k_c1x1<<<dim3(1024,1,1), blk, 0, stream>>>(I2, se2_w, se2_b, rp1_w, rp1_b, Cq, Cv);
  k_dw  <<<dim3(4,52,16),  blk, 0, stream>>>(Cq, Cv, se2_dw, se2_db, rp1_dw, rp1_db, Qr, Vr);
  k_attn<<<dim3(NB*HGT,1,1), blk, 96*264*2 + 4*16*104*2 + 256*4, stream>>>(Ql, Qr, Vl, Vr);
  k_fuse<<<dim3(1024,1,1), blk, 0, stream>>>(I1, I2, Vr, Vl, Wcat, bv, OUT);
}